// Round 9
// baseline (157.499 us; speedup 1.0000x reference)
//
#include <hip/hip_runtime.h>
#include <hip/hip_bf16.h>
#include <cstdint>
#include <cstddef>

#define B_N   32
#define CIN_  128
#define COUT_ 128
#define KW_   7
#define L_    4096
#define PAD_  3
#define NW_   256      // w-positions per block tile (R5 geometry: 512 blocks, 2/CU)
#define RPB   4104     // exT rows per batch: r = l + 3, guards r<3 and r>4098
#define NWELEM (KW_ * COUT_ * CIN_)   // 114688
#define NGUARD (B_N * 8 * CIN_)       // 32768

#define SX_ROWS  264                  // 262 used (256 w + 6 taps); pad to 264
#define SX_ELEMS (SX_ROWS * CIN_)     // 33792 bf16 = 67584 B -> 2 blocks/CU

typedef __attribute__((ext_vector_type(8)))  short bf16x8;
typedef __attribute__((ext_vector_type(4)))  float f32x4;
typedef __attribute__((ext_vector_type(16))) float f32x16;

__device__ __forceinline__ void gl2lds16(const void* g, void* l) {
    __builtin_amdgcn_global_load_lds(
        (const __attribute__((address_space(1))) unsigned int*)g,
        (__attribute__((address_space(3))) unsigned int*)l, 16, 0, 0);
}

// exp+transpose of x (blocks x<64), plus weight-exp (written in 32x32x16 MFMA
// A-fragment order) and exT guard-row zeroing (blocks x>=64, y==0).
// ewb layout: idx = ((((t*8+ck)*4+oq)<<6) + l6)*8 + e holds
// exp(W[oq*32+(l6&31)][ck*16+(l6>>5)*8+e]) at tap t -- one A-fragment is a
// contiguous 1KB block, loaded as a single coalesced wave read into VGPRs.
__global__ __launch_bounds__(256) void exp_x_kernel(
        const float* __restrict__ x, __hip_bfloat16* __restrict__ exT,
        const float* __restrict__ w, __hip_bfloat16* __restrict__ ewb) {
    if (blockIdx.x >= 64) {
        if (blockIdx.y != 0) return;
        int base = (blockIdx.x - 64) * 256 + threadIdx.x;   // 18 blocks * 256 = 4608
        #pragma unroll
        for (int i = 0; i < 32; ++i) {
            int idx = base + 4608 * i;                      // covers 147456 = NWELEM+NGUARD
            if (idx < NWELEM) {
                int e   = idx & 7;
                int l6  = (idx >> 3) & 63;
                int frg = idx >> 9;                         // 0..223
                int oq  = frg & 3;
                int ck  = (frg >> 2) & 7;
                int t   = frg >> 5;                         // 0..6
                int o   = oq * 32 + (l6 & 31);
                int ch  = ck * 16 + ((l6 >> 5) << 3) + e;
                ewb[idx] = __float2bfloat16(__expf(w[(o * CIN_ + ch) * KW_ + t]));
            } else {
                int j  = idx - NWELEM;
                int b  = j >> 10, rr = (j >> 7) & 7, c = j & 127;
                int r  = (rr < 3) ? rr : (4096 + rr);       // rows 0,1,2 and 4099..4103
                exT[((size_t)b * RPB + r) * CIN_ + c] = __float2bfloat16(0.0f);
            }
        }
        return;
    }

    __shared__ __align__(16) __hip_bfloat16 tileT[64 * 136];   // 17408 B
    const int b  = blockIdx.y;
    const int l0 = blockIdx.x * 64;
    const int tid = threadIdx.x;
    const float* xb = x + (size_t)b * CIN_ * L_ + l0;

    #pragma unroll
    for (int i = 0; i < 8; ++i) {
        int idx = tid + 256 * i;
        int c   = idx >> 4;               // 0..127
        int lv4 = (idx & 15) * 4;         // l offset 0..60
        f32x4 v = *(const f32x4*)(xb + (size_t)c * L_ + lv4);
        #pragma unroll
        for (int k2 = 0; k2 < 4; ++k2) {
            int l  = lv4 + k2;
            int sw = (l >> 2) & 15;
            tileT[l * 136 + (c ^ (sw << 3))] = __float2bfloat16(__expf(v[k2]));
        }
    }
    __syncthreads();

    __hip_bfloat16* dst = exT + ((size_t)b * RPB + l0 + PAD_) * CIN_;
    #pragma unroll
    for (int i = 0; i < 4; ++i) {
        int idx = tid + 256 * i;
        int l  = idx >> 4;                // 16 lanes per row -> 256 B coalesced
        int gc = idx & 15;                // channel granule (8 ch)
        int sw = (l >> 2) & 15;
        bf16x8 vv = *(const bf16x8*)&tileT[l * 136 + ((gc ^ sw) << 3)];
        *(bf16x8*)(dst + (size_t)l * CIN_ + gc * 8) = vv;
    }
}

// Conv GEMM, Round 9: R5 geometry (NW=256, 512 blocks, 2/CU, ONE barrier,
// B-only LDS) with the inner loop rebuilt for latency cover:
//  - mfma_f32_32x32x16_bf16: same operand bytes/FLOP, ~20% higher measured
//    ceiling (2495 vs 2075 TF), 4x fewer MFMA instrs. Wave tile 64o x 128w
//    = 2x4 tiles of 32x32, acc 2x4xf32x16 = 128 VGPRs.
//  - 3-deep rotating A-prefetch (afq[4], full unroll -> static indices):
//    since A bypasses LDS, no barrier ever drains its vmcnt -- the compiler
//    emits COUNTED vmcnt on the register dependency (the T4 pattern),
//    giving ~3 phases (~500+ cyc) of L2-latency cover. All R1-R8 variants
//    had <=1 phase of cover; MfmaUtil pinned at ~25% = exposed latency.
//  - 56 barrier-free phases: {2 A-loads(ph+3) global, 4 B ds_reads, 8 MFMA}.
//  - B slot swizzle widened to j^(p&15): 32 rows/B-frag spread over all 16
//    slots, 2 lanes/quad (free); same involution staged and read.
//  - setprio dropped (null-to-negative without deep phase split, m190).
__global__ __launch_bounds__(256, 2) void tropconv_kernel(
        const __hip_bfloat16* __restrict__ exT,
        const __hip_bfloat16* __restrict__ ewb,
        const float* __restrict__ bias,
        float* __restrict__ out) {
    __shared__ __align__(16) __hip_bfloat16 sX[SX_ELEMS];   // 67584 B

    const int tid  = threadIdx.x;
    const int lane = tid & 63;
    const int wave = tid >> 6;
    const int wm   = wave >> 1;            // 0..1: o half (64 each)
    const int wn   = wave & 1;             // 0..1: w half (128 each)
    const int l31  = lane & 31;
    const int h    = lane >> 5;            // k-half selector

    const int b  = blockIdx.y;
    const int w0 = blockIdx.x * NW_;
    const __hip_bfloat16* exb = exT + ((size_t)b * RPB + w0) * CIN_;

    // ---- stage X once: 264 rows x 16 granules = 4224 granules.
    // LDS slot s of row p holds channel-granule s^(p&15) (involution).
    #pragma unroll
    for (int s = 0; s < 16; ++s) {
        int gx = tid + 256 * s;
        int p = gx >> 4, j = gx & 15;
        gl2lds16(exb + (p << 7) + ((j ^ (p & 15)) << 3), &sX[gx * 8]);
    }
    if (tid < 128) {                       // rows 256..263; waves 0,1 fully active
        int gx = tid + 4096;
        int p = gx >> 4, j = gx & 15;
        gl2lds16(exb + (p << 7) + ((j ^ (p & 15)) << 3), &sX[gx * 8]);
    }

    f32x16 acc[2][4];
    #pragma unroll
    for (int i = 0; i < 2; ++i)
        #pragma unroll
        for (int j = 0; j < 4; ++j)
            #pragma unroll
            for (int r = 0; r < 16; ++r)
                acc[i][j][r] = 0.f;

    // A-frag for phase P (t=P%7, ck=P/7), o-tile oq=wm*2+mi: contiguous 1KB.
    // Data for phase P lives in rotating set afq[P&3]; loaded 3 phases early.
    bf16x8 afq[4][2];
#define ALOADP(P)                                                            \
    do {                                                                     \
        if ((P) < 56) {                                                      \
            _Pragma("unroll")                                                \
            for (int mi = 0; mi < 2; ++mi)                                   \
                afq[(P) & 3][mi] = *(const bf16x8*)&ewb[                     \
                    (((((P) % 7) * 8 + (P) / 7) * 4 + wm * 2 + mi) << 9)     \
                    + lane * 8];                                             \
        }                                                                    \
    } while (0)

    // prologue A-loads issue BEFORE the barrier: they overlap the staging
    // drain (barrier's vmcnt(0) covers them; they're long done by phase 0).
    ALOADP(0); ALOADP(1); ALOADP(2);

    __syncthreads();                       // the block's ONE barrier

    #pragma unroll
    for (int ph = 0; ph < 56; ++ph) {
        ALOADP(ph + 3);                    // issue 3 phases ahead (counted vmcnt)
        const int t_  = ph % 7;
        const int ck_ = ph / 7;
        bf16x8 bx[4];
        #pragma unroll
        for (int ni = 0; ni < 4; ++ni) {   // B: col=l31 (w pos), k=ck*16+h*8
            int p = wn * 128 + ni * 32 + l31 + t_;
            int s = (ck_ * 2 + h) ^ (p & 15);
            bx[ni] = *(const bf16x8*)&sX[(p << 7) + (s << 3)];
        }
        #pragma unroll
        for (int mi = 0; mi < 2; ++mi)
            #pragma unroll
            for (int ni = 0; ni < 4; ++ni)
                acc[mi][ni] = __builtin_amdgcn_mfma_f32_32x32x16_bf16(
                    afq[ph & 3][mi], bx[ni], acc[mi][ni], 0, 0, 0);
    }
#undef ALOADP

    // epilogue: y = log(s) + bias[o].
    // 32x32 C/D: col = lane&31 (w), row = (r&3) + 8*(r>>2) + 4*h (cout).
    float* outb = out + (size_t)b * COUT_ * L_;
    #pragma unroll
    for (int mi = 0; mi < 2; ++mi) {
        #pragma unroll
        for (int r = 0; r < 16; ++r) {
            int o = (wm * 2 + mi) * 32 + (r & 3) + 8 * (r >> 2) + 4 * h;
            float bv = bias[o];
            #pragma unroll
            for (int ni = 0; ni < 4; ++ni) {
                int w = w0 + wn * 128 + ni * 32 + l31;
                outb[(size_t)o * L_ + w] = __logf(acc[mi][ni][r]) + bv;
            }
        }
    }
}

extern "C" void kernel_launch(void* const* d_in, const int* in_sizes, int n_in,
                              void* d_out, int out_size, void* d_ws, size_t ws_size,
                              hipStream_t stream) {
    const float* x    = (const float*)d_in[0];   // (32,128,4096) f32
    const float* wgt  = (const float*)d_in[1];   // (128,128,7)   f32
    const float* bias = (const float*)d_in[2];   // (128,)        f32
    float* out = (float*)d_out;                  // (32,128,4096) f32

    // workspace: exT (32 x 4104 x 128 bf16 = 33,619,968 B), then ewb (229 KB)
    __hip_bfloat16* exT = (__hip_bfloat16*)d_ws;
    __hip_bfloat16* ewb = (__hip_bfloat16*)((char*)d_ws + (size_t)B_N * RPB * CIN_ * 2);

    exp_x_kernel<<<dim3(64 + 18, B_N), 256, 0, stream>>>(x, exT, wgt, ewb);
    tropconv_kernel<<<dim3(L_ / NW_, B_N), 256, 0, stream>>>(exT, ewb, bias, out);
}